// Round 2
// baseline (159.373 us; speedup 1.0000x reference)
//
#include <hip/hip_runtime.h>

#define NROWS 131072
#define D 64
#define K 1024

typedef __attribute__((ext_vector_type(8))) short short8;
typedef __attribute__((ext_vector_type(4))) float f32x4;
typedef unsigned int u32;

// ws layout (bytes):
//   [0, 131072)        ehT  ushort[1024][64]  bf16 codebook, [code][d]
//   [131072, 135168)   e2g  float[1024]       = -0.5*||e_k||^2
//   [135168, 139264)   hist int[1024]
//   [139264, 155648)   wavesum float[512]  (one per score block)

__device__ __forceinline__ unsigned short f2bf_rne(float f) {
    u32 u = __float_as_uint(f);
    u += 0x7fff + ((u >> 16) & 1);   // round-to-nearest-even
    return (unsigned short)(u >> 16);
}

__device__ __forceinline__ float b2f(short s) {
    return __uint_as_float(((u32)(unsigned short)s) << 16);
}

// 16 blocks x 256 threads: block handles 64 codes, thread = (code, d-quarter).
// 4x more blocks than before -> load latency overlapped across CUs.
__global__ __launch_bounds__(256) void prep_kernel(const float* __restrict__ E,
                                                   unsigned short* __restrict__ ehT,
                                                   float* __restrict__ e2g,
                                                   int* __restrict__ hist) {
    __shared__ float ps[4][64];
    const int lane = threadIdx.x & 63;          // code offset within block
    const int w = threadIdx.x >> 6;             // d-quarter 0..3
    const int k = blockIdx.x * 64 + lane;
    float s = 0.f;
#pragma unroll
    for (int half = 0; half < 2; ++half) {
        short8 h8;
#pragma unroll
        for (int j = 0; j < 8; ++j) {
            float v = E[(w * 16 + half * 8 + j) * K + k];   // coalesced across lanes
            s = fmaf(v, v, s);
            h8[j] = (short)f2bf_rne(v);
        }
        *(short8*)(ehT + (size_t)k * D + w * 16 + half * 8) = h8;
    }
    ps[w][lane] = s;
    __syncthreads();
    if (w == 0) e2g[k] = -0.5f * (ps[0][lane] + ps[1][lane] + ps[2][lane] + ps[3][lane]);
    if (threadIdx.x < 64) hist[blockIdx.x * 64 + threadIdx.x] = 0;
}

// R8: occupancy + fused epilogue. 512 blocks x 1024 threads (16 waves) =
// 2 blocks/CU (2048 thr = CU max; LDS ~42.6KB x2 < 160KB; VGPR capped <=64 by
// __launch_bounds__(1024,8)). 256 rows/block in 2 chunks of 128. Wave w owns
// codes [w*64,w*64+64) as persistent MFMA A-fragments; e2 float4 is the MFMA C
// operand. X staged once (issue-early fp32 load -> trunc-bf16 pack -> LDS frag
// order); epilogue fused per-chunk and fed from the SAME staged LDS slot:
// q = e_bf16 (== x + (e-x) to ulp), loss uses bf16 x (scalar perturbation
// ~1e-5, irrelevant vs 0.43 absmax) -> the 32MB X re-read is gone.
__global__ __launch_bounds__(1024, 8) void score_kernel(const float* __restrict__ X,
                                                        const unsigned short* __restrict__ ehT,
                                                        const float* __restrict__ e2g,
                                                        int* __restrict__ hist,
                                                        float* __restrict__ wavesum,
                                                        float* __restrict__ q) {
    __shared__ unsigned short xbuf[2][8192];   // 2 x 16 KB: 128 rows x 64 d, frag order
    __shared__ float mrg[128 * 17];            // per-row packed best per wave (stride 17)
    __shared__ int idxl[128];                  // winning code per row of current chunk
    __shared__ float redL[16];

    const int tid = threadIdx.x;
    const int wave = tid >> 6;
    const int lane = tid & 63;
    const int quad = lane >> 4;
    const int lc = lane & 15;
    const size_t row0 = (size_t)blockIdx.x * 256;

    // ---- persistent codebook fragments: wave owns codes [wave*64, wave*64+64) ----
    const int cbase = wave * 64;
    short8 ae[4][2];      // [code-tile][kslice], lane: code=tile*16+lc, d=ks*32+quad*8..+8
    f32x4 e2f[4];         // lane: -0.5||e||^2 for codes tile*16+quad*4..+4 (MFMA C operand)
    u32 cb4[4];
#pragma unroll
    for (int ct = 0; ct < 4; ++ct) {
        const unsigned short* ap = ehT + ((size_t)(cbase + ct * 16 + lc) << 6) + quad * 8;
        ae[ct][0] = *(const short8*)(ap);
        ae[ct][1] = *(const short8*)(ap + 32);
        e2f[ct] = *(const f32x4*)(e2g + cbase + ct * 16 + quad * 4);
        cb4[ct] = (u32)(cbase + ct * 16 + quad * 4);
    }

    // ---- stage mapping: thread n -> LDS 16B unit n = (t=n>>7, o=(n>>4)&7, ls=n&15)
    // holding bf16 X[t*16+ls][o*8..+8]; global float4-pair read is fully coalesced.
    const int st = tid >> 7, so = (tid >> 4) & 7, sl = tid & 15;
    const float* sbase = X + (row0 + (size_t)(st * 16 + sl)) * D + so * 8;

    // ---- prologue: stage chunk 0 ----
    float4 La = *(const float4*)(sbase);
    float4 Lb = *(const float4*)(sbase + 4);
    {
        union { u32 u[4]; short8 v; } pk;
        pk.u[0] = __builtin_amdgcn_perm(__float_as_uint(La.y), __float_as_uint(La.x), 0x07060302);
        pk.u[1] = __builtin_amdgcn_perm(__float_as_uint(La.w), __float_as_uint(La.z), 0x07060302);
        pk.u[2] = __builtin_amdgcn_perm(__float_as_uint(Lb.y), __float_as_uint(Lb.x), 0x07060302);
        pk.u[3] = __builtin_amdgcn_perm(__float_as_uint(Lb.w), __float_as_uint(Lb.z), 0x07060302);
        *(short8*)((char*)&xbuf[0][0] + tid * 16) = pk.v;
    }
    __syncthreads();

    float ls = 0.f;
    for (int c = 0; c < 2; ++c) {
        // issue-early global loads for chunk 1 (land during chunk-0 compute)
        if (c == 0) {
            La = *(const float4*)(sbase + 8192);
            Lb = *(const float4*)(sbase + 8192 + 4);
        }

        // ---- compute chunk c: 8 row-tiles x 4 code-tiles ----
        const char* bb = (const char*)&xbuf[c][0];
#pragma unroll 2
        for (int t = 0; t < 8; ++t) {
            const char* bp = bb + t * 2048 + quad * 256 + lc * 16;
            short8 b0 = *(const short8*)(bp);           // ks0, contiguous 1KB/wave
            short8 b1 = *(const short8*)(bp + 1024);    // ks1
            float bt = -3.4e38f;
#pragma unroll
            for (int ct = 0; ct < 4; ++ct) {
                f32x4 acc = __builtin_amdgcn_mfma_f32_16x16x32_bf16(ae[ct][0], b0, e2f[ct], 0, 0, 0);
                acc = __builtin_amdgcn_mfma_f32_16x16x32_bf16(ae[ct][1], b1, acc, 0, 0, 0);
                // acc[r] = score(code = cb4[ct]+r, xrow = t*16+lc); pack (score|code)
                float p0 = __uint_as_float((__float_as_uint(acc[0]) & 0xFFFFFC00u) | (cb4[ct] + 0));
                float p1 = __uint_as_float((__float_as_uint(acc[1]) & 0xFFFFFC00u) | (cb4[ct] + 1));
                float p2 = __uint_as_float((__float_as_uint(acc[2]) & 0xFFFFFC00u) | (cb4[ct] + 2));
                float p3 = __uint_as_float((__float_as_uint(acc[3]) & 0xFFFFFC00u) | (cb4[ct] + 3));
                bt = fmaxf(bt, fmaxf(p0, p1));   // v_max3
                bt = fmaxf(bt, fmaxf(p2, p3));   // v_max3
            }
            // reduce over the 4 quad-groups (codes) sharing xrow = lc
            bt = fmaxf(bt, __shfl_xor(bt, 16, 64));
            bt = fmaxf(bt, __shfl_xor(bt, 32, 64));
            if (lane < 16) mrg[(t * 16 + lane) * 17 + wave] = bt;
        }
        __syncthreads();   // mrg visible

        // ---- cross-wave merge + hist (2 waves) ∥ stage-write chunk 1 (all) ----
        if (tid < 128) {
            float m = mrg[tid * 17];
#pragma unroll
            for (int w = 1; w < 16; ++w) m = fmaxf(m, mrg[tid * 17 + w]);
            int kk = (int)(__float_as_uint(m) & 1023u);
            idxl[tid] = kk;
            atomicAdd(&hist[kk], 1);
        }
        if (c == 0) {
            union { u32 u[4]; short8 v; } pk;
            pk.u[0] = __builtin_amdgcn_perm(__float_as_uint(La.y), __float_as_uint(La.x), 0x07060302);
            pk.u[1] = __builtin_amdgcn_perm(__float_as_uint(La.w), __float_as_uint(La.z), 0x07060302);
            pk.u[2] = __builtin_amdgcn_perm(__float_as_uint(Lb.y), __float_as_uint(Lb.x), 0x07060302);
            pk.u[3] = __builtin_amdgcn_perm(__float_as_uint(Lb.w), __float_as_uint(Lb.z), 0x07060302);
            *(short8*)((char*)&xbuf[1][0] + tid * 16) = pk.v;
        }
        __syncthreads();   // idxl + staged chunk visible

        // ---- fused epilogue for chunk c: thread handles its own staged slice ----
        {
            int kk = idxl[st * 16 + sl];                  // broadcast among 8 so-threads
            short8 ev = *(const short8*)(ehT + ((size_t)kk << 6) + so * 8);
            short8 xv = *(const short8*)(&xbuf[c][tid * 8]);
            float4 qa, qb;
            float e0, x0, dd;
            e0 = b2f(ev[0]); x0 = b2f(xv[0]); dd = e0 - x0; ls = fmaf(dd, dd, ls); qa.x = e0;
            e0 = b2f(ev[1]); x0 = b2f(xv[1]); dd = e0 - x0; ls = fmaf(dd, dd, ls); qa.y = e0;
            e0 = b2f(ev[2]); x0 = b2f(xv[2]); dd = e0 - x0; ls = fmaf(dd, dd, ls); qa.z = e0;
            e0 = b2f(ev[3]); x0 = b2f(xv[3]); dd = e0 - x0; ls = fmaf(dd, dd, ls); qa.w = e0;
            e0 = b2f(ev[4]); x0 = b2f(xv[4]); dd = e0 - x0; ls = fmaf(dd, dd, ls); qb.x = e0;
            e0 = b2f(ev[5]); x0 = b2f(xv[5]); dd = e0 - x0; ls = fmaf(dd, dd, ls); qb.y = e0;
            e0 = b2f(ev[6]); x0 = b2f(xv[6]); dd = e0 - x0; ls = fmaf(dd, dd, ls); qb.z = e0;
            e0 = b2f(ev[7]); x0 = b2f(xv[7]); dd = e0 - x0; ls = fmaf(dd, dd, ls); qb.w = e0;
            float* qp = q + (row0 + (size_t)(st * 16 + sl)) * D + so * 8 + (size_t)c * 8192;
            *(float4*)(qp) = qa;
            *(float4*)(qp + 4) = qb;
        }
        // no barrier needed: chunk-1 compute reads xbuf[1] (staged before the
        // barrier above); nothing overwrites xbuf[0]/idxl until after the next
        // full barrier pair.
    }

    // ---- block loss reduction ----
    for (int off = 32; off > 0; off >>= 1) ls += __shfl_down(ls, off, 64);
    if (lane == 0) redL[wave] = ls;
    __syncthreads();
    if (tid == 0) {
        float L = 0.f;
#pragma unroll
        for (int i = 0; i < 16; ++i) L += redL[i];
        wavesum[blockIdx.x] = L;
    }
}

__global__ __launch_bounds__(1024) void finalize_kernel(const int* __restrict__ hist,
                                                        const float* __restrict__ wavesum,
                                                        float* __restrict__ out) {
    __shared__ float redH[16], redL[16];
    int tid = threadIdx.x;
    float p = (float)hist[tid] * (1.0f / (float)NROWS);
    float term = p * logf(p + 1e-10f);
    float ls = (tid < 512) ? wavesum[tid] : 0.f;
    for (int off = 32; off > 0; off >>= 1) {
        term += __shfl_down(term, off, 64);
        ls += __shfl_down(ls, off, 64);
    }
    int lane = tid & 63, wid = tid >> 6;
    if (lane == 0) { redH[wid] = term; redL[wid] = ls; }
    __syncthreads();
    if (tid == 0) {
        float H = 0.f, L = 0.f;
#pragma unroll
        for (int i = 0; i < 16; ++i) { H += redH[i]; L += redL[i]; }
        out[(size_t)NROWS * D + 0] = 2.0f * (L / (float)(NROWS * D));
        out[(size_t)NROWS * D + 1] = expf(-H);
    }
}

extern "C" void kernel_launch(void* const* d_in, const int* in_sizes, int n_in,
                              void* d_out, int out_size, void* d_ws, size_t ws_size,
                              hipStream_t stream) {
    const float* X = (const float*)d_in[0];   // [64,2048,64] fp32
    const float* E = (const float*)d_in[1];   // [64,1024]   fp32
    float* out = (float*)d_out;

    char* w = (char*)d_ws;
    unsigned short* ehT = (unsigned short*)(w + 0);
    float* e2g          = (float*)(w + 131072);
    int* hist           = (int*)(w + 135168);
    float* wavesum      = (float*)(w + 139264);

    prep_kernel<<<16, 256, 0, stream>>>(E, ehT, e2g, hist);
    score_kernel<<<512, 1024, 0, stream>>>(X, ehT, e2g, hist, wavesum, out);
    finalize_kernel<<<1, 1024, 0, stream>>>(hist, wavesum, out);
}

// Round 3
// 135.948 us; speedup vs baseline: 1.1723x; 1.1723x over previous
//
#include <hip/hip_runtime.h>

#define NROWS 131072
#define D 64
#define K 1024

typedef __attribute__((ext_vector_type(8))) short short8;
typedef __attribute__((ext_vector_type(4))) float f32x4;
typedef unsigned int u32;

// ws layout (bytes):
//   [0, 131072)        ehT  ushort[1024][64]  bf16 codebook, [code][d]
//   [131072, 135168)   e2g  float[1024]       = -0.5*||e_k||^2
//   [135168, 139264)   hist int[1024]
//   [139264, 155648)   wavesum float[512]  (one per score block)

__device__ __forceinline__ unsigned short f2bf_rne(float f) {
    u32 u = __float_as_uint(f);
    u += 0x7fff + ((u >> 16) & 1);   // round-to-nearest-even
    return (unsigned short)(u >> 16);
}

__device__ __forceinline__ float b2f(short s) {
    return __uint_as_float(((u32)(unsigned short)s) << 16);
}

// 16 blocks x 256 threads: block handles 64 codes, thread = (code, d-quarter).
__global__ __launch_bounds__(256) void prep_kernel(const float* __restrict__ E,
                                                   unsigned short* __restrict__ ehT,
                                                   float* __restrict__ e2g,
                                                   int* __restrict__ hist) {
    __shared__ float ps[4][64];
    const int lane = threadIdx.x & 63;          // code offset within block
    const int w = threadIdx.x >> 6;             // d-quarter 0..3
    const int k = blockIdx.x * 64 + lane;
    float s = 0.f;
#pragma unroll
    for (int half = 0; half < 2; ++half) {
        short8 h8;
#pragma unroll
        for (int j = 0; j < 8; ++j) {
            float v = E[(w * 16 + half * 8 + j) * K + k];   // coalesced across lanes
            s = fmaf(v, v, s);
            h8[j] = (short)f2bf_rne(v);
        }
        *(short8*)(ehT + (size_t)k * D + w * 16 + half * 8) = h8;
    }
    ps[w][lane] = s;
    __syncthreads();
    if (w == 0) e2g[k] = -0.5f * (ps[0][lane] + ps[1][lane] + ps[2][lane] + ps[3][lane]);
    if (threadIdx.x < 64) hist[blockIdx.x * 64 + threadIdx.x] = 0;
}

// R9: R2's occupancy (512 blocks x 16 waves = 2 blocks/CU) with both R2
// poisons removed:
//  - no spills: both 128-row chunks staged up-front (stage regs die in the
//    prologue; no issue-early registers held across compute). In-loop live
//    set ~58 VGPR -> fits the 64-reg budget of __launch_bounds__(1024,8).
//  - coalesced epilogue (R1-proven mapping: 16 consecutive lanes = 256B
//    contiguous float4), x re-read from global (L3-resident; R1 FETCH=29MB),
//    pipelined as merge(c1) ∥ epilogue(c0). 4 barriers total.
// Numerics identical to R1/R2 (same fragments, same MFMA chain, same packed
// score|code argmax).
__global__ __launch_bounds__(1024, 8) void score_kernel(const float* __restrict__ X,
                                                        const unsigned short* __restrict__ ehT,
                                                        const float* __restrict__ e2g,
                                                        int* __restrict__ hist,
                                                        float* __restrict__ wavesum,
                                                        float* __restrict__ q) {
    __shared__ unsigned short xbuf[2][8192];   // 2 x 16 KB: 128 rows x 64 d, frag order
    __shared__ float mrg[2][128 * 17];         // per-row packed best per wave (stride 17)
    __shared__ int idxl[256];                  // winning code per row
    __shared__ float redL[16];

    const int tid = threadIdx.x;
    const int wave = tid >> 6;
    const int lane = tid & 63;
    const int quad = lane >> 4;
    const int lc = lane & 15;
    const size_t row0 = (size_t)blockIdx.x * 256;

    // ---- stage BOTH chunks: thread n -> LDS 16B unit n = (t=n>>7, o=(n>>4)&7,
    // ls=n&15) holding bf16 X[t*16+ls][o*8..+8]; global read fully coalesced.
    const int st = tid >> 7, so = (tid >> 4) & 7, sl = tid & 15;
    const float* sbase = X + (row0 + (size_t)(st * 16 + sl)) * D + so * 8;
#pragma unroll
    for (int c = 0; c < 2; ++c) {
        float4 La = *(const float4*)(sbase + c * 8192);
        float4 Lb = *(const float4*)(sbase + c * 8192 + 4);
        union { u32 u[4]; short8 v; } pk;
        pk.u[0] = __builtin_amdgcn_perm(__float_as_uint(La.y), __float_as_uint(La.x), 0x07060302);
        pk.u[1] = __builtin_amdgcn_perm(__float_as_uint(La.w), __float_as_uint(La.z), 0x07060302);
        pk.u[2] = __builtin_amdgcn_perm(__float_as_uint(Lb.y), __float_as_uint(Lb.x), 0x07060302);
        pk.u[3] = __builtin_amdgcn_perm(__float_as_uint(Lb.w), __float_as_uint(Lb.z), 0x07060302);
        *(short8*)((char*)&xbuf[c][0] + tid * 16) = pk.v;
    }

    // ---- persistent codebook fragments: wave owns codes [wave*64, wave*64+64) ----
    const int cbase = wave * 64;
    short8 ae[4][2];      // [code-tile][kslice]: code=tile*16+lc, d=ks*32+quad*8..+8
    f32x4 e2f[4];         // -0.5||e||^2 for codes tile*16+quad*4..+4 (MFMA C operand)
#pragma unroll
    for (int ct = 0; ct < 4; ++ct) {
        const unsigned short* ap = ehT + ((size_t)(cbase + ct * 16 + lc) << 6) + quad * 8;
        ae[ct][0] = *(const short8*)(ap);
        ae[ct][1] = *(const short8*)(ap + 32);
        e2f[ct] = *(const f32x4*)(e2g + cbase + ct * 16 + quad * 4);
    }
    const u32 cb0 = (u32)(cbase + quad * 4);

    __syncthreads();   // B1: both chunks staged

    // ---- compute macro: chunk c -> mrg[c] ----
    auto compute = [&](int c) {
        const char* bb = (const char*)&xbuf[c][0];
#pragma unroll 2
        for (int t = 0; t < 8; ++t) {
            const char* bp = bb + t * 2048 + quad * 256 + lc * 16;
            short8 b0 = *(const short8*)(bp);           // ks0
            short8 b1 = *(const short8*)(bp + 1024);    // ks1
            float bt = -3.4e38f;
#pragma unroll
            for (int ct = 0; ct < 4; ++ct) {
                f32x4 acc = __builtin_amdgcn_mfma_f32_16x16x32_bf16(ae[ct][0], b0, e2f[ct], 0, 0, 0);
                acc = __builtin_amdgcn_mfma_f32_16x16x32_bf16(ae[ct][1], b1, acc, 0, 0, 0);
                // acc[r] = score(code = cb0 + ct*16 + r, xrow = t*16+lc)
                float p0 = __uint_as_float((__float_as_uint(acc[0]) & 0xFFFFFC00u) | (cb0 + ct * 16 + 0));
                float p1 = __uint_as_float((__float_as_uint(acc[1]) & 0xFFFFFC00u) | (cb0 + ct * 16 + 1));
                float p2 = __uint_as_float((__float_as_uint(acc[2]) & 0xFFFFFC00u) | (cb0 + ct * 16 + 2));
                float p3 = __uint_as_float((__float_as_uint(acc[3]) & 0xFFFFFC00u) | (cb0 + ct * 16 + 3));
                bt = fmaxf(bt, fmaxf(p0, p1));   // v_max3
                bt = fmaxf(bt, fmaxf(p2, p3));   // v_max3
            }
            bt = fmaxf(bt, __shfl_xor(bt, 16, 64));
            bt = fmaxf(bt, __shfl_xor(bt, 32, 64));
            if (lane < 16) mrg[c][(t * 16 + lane) * 17 + wave] = bt;
        }
    };

    // ---- merge macro: mrg[c] -> idxl[c*128..), hist (128 threads) ----
    auto merge = [&](int c) {
        if (tid < 128) {
            float m = mrg[c][tid * 17];
#pragma unroll
            for (int w = 1; w < 16; ++w) m = fmaxf(m, mrg[c][tid * 17 + w]);
            int kk = (int)(__float_as_uint(m) & 1023u);
            idxl[c * 128 + tid] = kk;
            atomicAdd(&hist[kk], 1);
        }
    };

    // ---- epilogue macro: half h = rows h*128 .. h*128+128, coalesced ----
    float ls = 0.f;
    const int er = tid >> 4, el = tid & 15;
    auto epilogue = [&](int h) {
#pragma unroll
        for (int it = 0; it < 2; ++it) {
            int rl = h * 128 + it * 64 + er;
            int k = idxl[rl];                       // broadcast within 16-thread group
            size_t row = row0 + rl;
            float4 xv = *(const float4*)(X + row * D + el * 4);
            short4 ev = *(const short4*)((const char*)ehT + (size_t)k * 128 + el * 8);
            float4 o;
            float dd;
            dd = b2f(ev.x) - xv.x; ls = fmaf(dd, dd, ls); o.x = xv.x + dd;
            dd = b2f(ev.y) - xv.y; ls = fmaf(dd, dd, ls); o.y = xv.y + dd;
            dd = b2f(ev.z) - xv.z; ls = fmaf(dd, dd, ls); o.z = xv.z + dd;
            dd = b2f(ev.w) - xv.w; ls = fmaf(dd, dd, ls); o.w = xv.w + dd;
            *(float4*)(q + row * D + el * 4) = o;
        }
    };

    compute(0);
    __syncthreads();   // B2: mrg[0] visible
    merge(0);          // idxl[0..128)
    compute(1);
    __syncthreads();   // B3: mrg[1] + idxl[0..128) visible
    merge(1);          // idxl[128..256)   ∥ epilogue(0) on other threads
    epilogue(0);       // reads idxl[0..128) (written before B3; disjoint from merge(1) writes)
    __syncthreads();   // B4: idxl[128..256) visible
    epilogue(1);

    // ---- block loss reduction ----
    for (int off = 32; off > 0; off >>= 1) ls += __shfl_down(ls, off, 64);
    if (lane == 0) redL[wave] = ls;
    __syncthreads();
    if (tid == 0) {
        float L = 0.f;
#pragma unroll
        for (int i = 0; i < 16; ++i) L += redL[i];
        wavesum[blockIdx.x] = L;
    }
}

__global__ __launch_bounds__(1024) void finalize_kernel(const int* __restrict__ hist,
                                                        const float* __restrict__ wavesum,
                                                        float* __restrict__ out) {
    __shared__ float redH[16], redL[16];
    int tid = threadIdx.x;
    float p = (float)hist[tid] * (1.0f / (float)NROWS);
    float term = p * logf(p + 1e-10f);
    float ls = (tid < 512) ? wavesum[tid] : 0.f;
    for (int off = 32; off > 0; off >>= 1) {
        term += __shfl_down(term, off, 64);
        ls += __shfl_down(ls, off, 64);
    }
    int lane = tid & 63, wid = tid >> 6;
    if (lane == 0) { redH[wid] = term; redL[wid] = ls; }
    __syncthreads();
    if (tid == 0) {
        float H = 0.f, L = 0.f;
#pragma unroll
        for (int i = 0; i < 16; ++i) { H += redH[i]; L += redL[i]; }
        out[(size_t)NROWS * D + 0] = 2.0f * (L / (float)(NROWS * D));
        out[(size_t)NROWS * D + 1] = expf(-H);
    }
}

extern "C" void kernel_launch(void* const* d_in, const int* in_sizes, int n_in,
                              void* d_out, int out_size, void* d_ws, size_t ws_size,
                              hipStream_t stream) {
    const float* X = (const float*)d_in[0];   // [64,2048,64] fp32
    const float* E = (const float*)d_in[1];   // [64,1024]   fp32
    float* out = (float*)d_out;

    char* w = (char*)d_ws;
    unsigned short* ehT = (unsigned short*)(w + 0);
    float* e2g          = (float*)(w + 131072);
    int* hist           = (int*)(w + 135168);
    float* wavesum      = (float*)(w + 139264);

    prep_kernel<<<16, 256, 0, stream>>>(E, ehT, e2g, hist);
    score_kernel<<<512, 1024, 0, stream>>>(X, ehT, e2g, hist, wavesum, out);
    finalize_kernel<<<1, 1024, 0, stream>>>(hist, wavesum, out);
}

// Round 4
// 132.392 us; speedup vs baseline: 1.2038x; 1.0269x over previous
//
#include <hip/hip_runtime.h>

#define NROWS 131072
#define D 64
#define K 1024

typedef __attribute__((ext_vector_type(8))) short short8;
typedef __attribute__((ext_vector_type(4))) float f32x4;
typedef unsigned int u32;

// ws layout (bytes):
//   [0, 131072)        ehT  ushort[1024][64]  bf16 codebook, [code][d]
//   [131072, 135168)   e2g  float[1024]       = -0.5*||e_k||^2
//   [135168, 139264)   hist int[1024]
//   [139264, 155648)   wavesum float[512]  (one per score block)

__device__ __forceinline__ unsigned short f2bf_rne(float f) {
    u32 u = __float_as_uint(f);
    u += 0x7fff + ((u >> 16) & 1);   // round-to-nearest-even
    return (unsigned short)(u >> 16);
}

__device__ __forceinline__ float b2f(short s) {
    return __uint_as_float(((u32)(unsigned short)s) << 16);
}

// 16 blocks x 256 threads: block handles 64 codes, thread = (code, d-quarter).
__global__ __launch_bounds__(256) void prep_kernel(const float* __restrict__ E,
                                                   unsigned short* __restrict__ ehT,
                                                   float* __restrict__ e2g,
                                                   int* __restrict__ hist) {
    __shared__ float ps[4][64];
    const int lane = threadIdx.x & 63;          // code offset within block
    const int w = threadIdx.x >> 6;             // d-quarter 0..3
    const int k = blockIdx.x * 64 + lane;
    float s = 0.f;
#pragma unroll
    for (int half = 0; half < 2; ++half) {
        short8 h8;
#pragma unroll
        for (int j = 0; j < 8; ++j) {
            float v = E[(w * 16 + half * 8 + j) * K + k];   // coalesced across lanes
            s = fmaf(v, v, s);
            h8[j] = (short)f2bf_rne(v);
        }
        *(short8*)(ehT + (size_t)k * D + w * 16 + half * 8) = h8;
    }
    ps[w][lane] = s;
    __syncthreads();
    if (w == 0) e2g[k] = -0.5f * (ps[0][lane] + ps[1][lane] + ps[2][lane] + ps[3][lane]);
    if (threadIdx.x < 64) hist[blockIdx.x * 64 + threadIdx.x] = 0;
}

// R10: 512 blocks x 512 threads (8 waves) = 2 independent barrier groups/CU.
// __launch_bounds__(512,4) -> 128-VGPR budget (R2/R3 lesson: a 64-reg cap
// AGPR-splits/spills the persistent fragment set -> never cap below 128).
// Wave owns 128 codes (8 A-frag tiles = 64 VGPR); -0.5||e||^2 lives in LDS
// (e2s, broadcast reads) instead of 32 more VGPRs -> peak ~90 regs.
// 256 rows/block in 2 chunks of 128, both staged up-front; row-tiles stream
// from LDS and are reused against 8 code-tiles (2x the reuse of R1 -> half
// the LDS traffic per row x code). 4 barriers/block; merge's hist-atomic
// latency overlaps compute(1)/epilogue(0) and the co-resident second block.
// Numerics bitwise-identical to R1/R3 (same operands, chain, packed argmax).
__global__ __launch_bounds__(512, 4) void score_kernel(const float* __restrict__ X,
                                                       const unsigned short* __restrict__ ehT,
                                                       const float* __restrict__ e2g,
                                                       int* __restrict__ hist,
                                                       float* __restrict__ wavesum,
                                                       float* __restrict__ q) {
    __shared__ unsigned short xbuf[2][8192];   // 2 x 16 KB: 128 rows x 64 d, frag order
    __shared__ float e2s[1024];                // -0.5||e||^2, block-shared
    __shared__ float mrg[2][128 * 9];          // per-row packed best per wave (stride 9)
    __shared__ int idxl[256];                  // winning code per row
    __shared__ float redL[8];

    const int tid = threadIdx.x;               // 0..511
    const int wave = tid >> 6;                 // 0..7
    const int lane = tid & 63;
    const int quad = lane >> 4;
    const int lc = lane & 15;
    const size_t row0 = (size_t)blockIdx.x * 256;

    // ---- stage BOTH chunks: 16B unit m of chunk c = (t=m>>7, o=(m>>4)&7,
    // ls=m&15) holds bf16 X[c*128 + t*16+ls][o*8..+8]; thread does units
    // {tid, tid+512} of each chunk. Global reads coalesced (paired float4).
#pragma unroll
    for (int c = 0; c < 2; ++c)
#pragma unroll
        for (int h = 0; h < 2; ++h) {
            int m = h * 512 + tid;
            int tt = m >> 7, oo = (m >> 4) & 7, ll = m & 15;
            const float* xp = X + (row0 + (size_t)(c * 128 + tt * 16 + ll)) * D + oo * 8;
            float4 La = *(const float4*)(xp);
            float4 Lb = *(const float4*)(xp + 4);
            union { u32 u[4]; short8 v; } pk;
            pk.u[0] = __builtin_amdgcn_perm(__float_as_uint(La.y), __float_as_uint(La.x), 0x07060302);
            pk.u[1] = __builtin_amdgcn_perm(__float_as_uint(La.w), __float_as_uint(La.z), 0x07060302);
            pk.u[2] = __builtin_amdgcn_perm(__float_as_uint(Lb.y), __float_as_uint(Lb.x), 0x07060302);
            pk.u[3] = __builtin_amdgcn_perm(__float_as_uint(Lb.w), __float_as_uint(Lb.z), 0x07060302);
            *(short8*)((char*)&xbuf[c][0] + m * 16) = pk.v;
        }
    e2s[tid] = e2g[tid];
    e2s[tid + 512] = e2g[tid + 512];

    // ---- persistent codebook fragments: wave owns codes [wave*128, +128) ----
    const int cbase = wave * 128;
    short8 ae[8][2];      // [code-tile][kslice]: code=tile*16+lc, d=ks*32+quad*8..+8
#pragma unroll
    for (int ct = 0; ct < 8; ++ct) {
        const unsigned short* ap = ehT + ((size_t)(cbase + ct * 16 + lc) << 6) + quad * 8;
        ae[ct][0] = *(const short8*)(ap);
        ae[ct][1] = *(const short8*)(ap + 32);
    }
    const u32 cb0 = (u32)(cbase + quad * 4);

    __syncthreads();   // B1: chunks + e2s staged

    // ---- compute macro: chunk c -> mrg[c] ----
    auto compute = [&](int c) {
        const char* bb = (const char*)&xbuf[c][0];
#pragma unroll 2
        for (int t = 0; t < 8; ++t) {
            const char* bp = bb + t * 2048 + quad * 256 + lc * 16;
            short8 b0 = *(const short8*)(bp);           // ks0: row t*16+lc, d quad*8..+8
            short8 b1 = *(const short8*)(bp + 1024);    // ks1
            float bt = -3.4e38f;
#pragma unroll
            for (int ct = 0; ct < 8; ++ct) {
                f32x4 e2v = *(const f32x4*)(&e2s[cbase + ct * 16 + quad * 4]);  // broadcast
                f32x4 acc = __builtin_amdgcn_mfma_f32_16x16x32_bf16(ae[ct][0], b0, e2v, 0, 0, 0);
                acc = __builtin_amdgcn_mfma_f32_16x16x32_bf16(ae[ct][1], b1, acc, 0, 0, 0);
                // acc[r] = score(code = cb0 + ct*16 + r, xrow = t*16+lc)
                float p0 = __uint_as_float((__float_as_uint(acc[0]) & 0xFFFFFC00u) | (cb0 + ct * 16 + 0));
                float p1 = __uint_as_float((__float_as_uint(acc[1]) & 0xFFFFFC00u) | (cb0 + ct * 16 + 1));
                float p2 = __uint_as_float((__float_as_uint(acc[2]) & 0xFFFFFC00u) | (cb0 + ct * 16 + 2));
                float p3 = __uint_as_float((__float_as_uint(acc[3]) & 0xFFFFFC00u) | (cb0 + ct * 16 + 3));
                bt = fmaxf(bt, fmaxf(p0, p1));   // v_max3
                bt = fmaxf(bt, fmaxf(p2, p3));   // v_max3
            }
            // reduce over the 4 quad-groups (codes) sharing xrow = lc
            bt = fmaxf(bt, __shfl_xor(bt, 16, 64));
            bt = fmaxf(bt, __shfl_xor(bt, 32, 64));
            if (lane < 16) mrg[c][(t * 16 + lane) * 9 + wave] = bt;
        }
    };

    // ---- merge macro: mrg[c] -> idxl[c*128..), hist (waves 0-1) ----
    auto merge = [&](int c) {
        if (tid < 128) {
            float m = mrg[c][tid * 9];
#pragma unroll
            for (int w = 1; w < 8; ++w) m = fmaxf(m, mrg[c][tid * 9 + w]);
            int kk = (int)(__float_as_uint(m) & 1023u);
            idxl[c * 128 + tid] = kk;
            atomicAdd(&hist[kk], 1);
        }
    };

    // ---- epilogue macro: half h = rows h*128..+128; 16 thr/row, coalesced ----
    float ls = 0.f;
    const int er = tid >> 4, el = tid & 15;    // er 0..31
    auto epilogue = [&](int h) {
#pragma unroll
        for (int it = 0; it < 4; ++it) {
            int rl = h * 128 + it * 32 + er;
            int k = idxl[rl];                  // broadcast within 16-thread group
            size_t row = row0 + rl;
            float4 xv = *(const float4*)(X + row * D + el * 4);
            short4 ev = *(const short4*)((const char*)ehT + (size_t)k * 128 + el * 8);
            float4 o;
            float dd;
            dd = b2f(ev.x) - xv.x; ls = fmaf(dd, dd, ls); o.x = xv.x + dd;
            dd = b2f(ev.y) - xv.y; ls = fmaf(dd, dd, ls); o.y = xv.y + dd;
            dd = b2f(ev.z) - xv.z; ls = fmaf(dd, dd, ls); o.z = xv.z + dd;
            dd = b2f(ev.w) - xv.w; ls = fmaf(dd, dd, ls); o.w = xv.w + dd;
            *(float4*)(q + row * D + el * 4) = o;
        }
    };

    compute(0);
    __syncthreads();   // B2: mrg[0] visible
    merge(0);          // waves 0-1: idxl[0..128) + hist; then they join compute(1)
    compute(1);        // waves 2-7 start immediately (disjoint from merge(0))
    __syncthreads();   // B3: mrg[1] + idxl[0..128) visible
    merge(1);          // waves 0-1: idxl[128..256)
    epilogue(0);       // all waves; reads idxl[0..128)
    __syncthreads();   // B4: idxl[128..256) visible
    epilogue(1);

    // ---- block loss reduction ----
    for (int off = 32; off > 0; off >>= 1) ls += __shfl_down(ls, off, 64);
    if (lane == 0) redL[wave] = ls;
    __syncthreads();
    if (tid == 0) {
        float L = 0.f;
#pragma unroll
        for (int i = 0; i < 8; ++i) L += redL[i];
        wavesum[blockIdx.x] = L;
    }
}

__global__ __launch_bounds__(1024) void finalize_kernel(const int* __restrict__ hist,
                                                        const float* __restrict__ wavesum,
                                                        float* __restrict__ out) {
    __shared__ float redH[16], redL[16];
    int tid = threadIdx.x;
    float p = (float)hist[tid] * (1.0f / (float)NROWS);
    float term = p * logf(p + 1e-10f);
    float ls = (tid < 512) ? wavesum[tid] : 0.f;
    for (int off = 32; off > 0; off >>= 1) {
        term += __shfl_down(term, off, 64);
        ls += __shfl_down(ls, off, 64);
    }
    int lane = tid & 63, wid = tid >> 6;
    if (lane == 0) { redH[wid] = term; redL[wid] = ls; }
    __syncthreads();
    if (tid == 0) {
        float H = 0.f, L = 0.f;
#pragma unroll
        for (int i = 0; i < 16; ++i) { H += redH[i]; L += redL[i]; }
        out[(size_t)NROWS * D + 0] = 2.0f * (L / (float)(NROWS * D));
        out[(size_t)NROWS * D + 1] = expf(-H);
    }
}

extern "C" void kernel_launch(void* const* d_in, const int* in_sizes, int n_in,
                              void* d_out, int out_size, void* d_ws, size_t ws_size,
                              hipStream_t stream) {
    const float* X = (const float*)d_in[0];   // [64,2048,64] fp32
    const float* E = (const float*)d_in[1];   // [64,1024]   fp32
    float* out = (float*)d_out;

    char* w = (char*)d_ws;
    unsigned short* ehT = (unsigned short*)(w + 0);
    float* e2g          = (float*)(w + 131072);
    int* hist           = (int*)(w + 135168);
    float* wavesum      = (float*)(w + 139264);

    prep_kernel<<<16, 256, 0, stream>>>(E, ehT, e2g, hist);
    score_kernel<<<512, 512, 0, stream>>>(X, ehT, e2g, hist, wavesum, out);
    finalize_kernel<<<1, 1024, 0, stream>>>(hist, wavesum, out);
}

// Round 5
// 126.532 us; speedup vs baseline: 1.2596x; 1.0463x over previous
//
#include <hip/hip_runtime.h>

#define NROWS 131072
#define D 64
#define K 1024

typedef __attribute__((ext_vector_type(8))) short short8;
typedef __attribute__((ext_vector_type(4))) float f32x4;
typedef unsigned int u32;

// ws layout (bytes):
//   [0, 131072)        ehT  ushort[1024][64]  bf16 codebook, [code][d]
//   [131072, 135168)   e2g  float[1024]       = -0.5*||e_k||^2
//   [135168, 139264)   hist int[1024]
//   [139264, 155648)   wavesum float[512]  (one per score block)

__device__ __forceinline__ unsigned short f2bf_rne(float f) {
    u32 u = __float_as_uint(f);
    u += 0x7fff + ((u >> 16) & 1);   // round-to-nearest-even
    return (unsigned short)(u >> 16);
}

__device__ __forceinline__ float b2f(short s) {
    return __uint_as_float(((u32)(unsigned short)s) << 16);
}

// 16 blocks x 256 threads: block handles 64 codes, thread = (code, d-quarter).
__global__ __launch_bounds__(256) void prep_kernel(const float* __restrict__ E,
                                                   unsigned short* __restrict__ ehT,
                                                   float* __restrict__ e2g,
                                                   int* __restrict__ hist) {
    __shared__ float ps[4][64];
    const int lane = threadIdx.x & 63;          // code offset within block
    const int w = threadIdx.x >> 6;             // d-quarter 0..3
    const int k = blockIdx.x * 64 + lane;
    float s = 0.f;
#pragma unroll
    for (int half = 0; half < 2; ++half) {
        short8 h8;
#pragma unroll
        for (int j = 0; j < 8; ++j) {
            float v = E[(w * 16 + half * 8 + j) * K + k];   // coalesced across lanes
            s = fmaf(v, v, s);
            h8[j] = (short)f2bf_rne(v);
        }
        *(short8*)(ehT + (size_t)k * D + w * 16 + half * 8) = h8;
    }
    ps[w][lane] = s;
    __syncthreads();
    if (w == 0) e2g[k] = -0.5f * (ps[0][lane] + ps[1][lane] + ps[2][lane] + ps[3][lane]);
    if (threadIdx.x < 64) hist[blockIdx.x * 64 + threadIdx.x] = 0;
}

// R11 = R3's schedule with the register poison removed.
// LESSON (R2/R3/R4): the VGPR file is 512 regs/SIMD, and the __launch_bounds__
// min-waves arg imposes a TOTAL (arch+acc, gfx950 unified) cap of 512/min_waves.
// Any cap <= the ~75-reg working set makes the allocator split/spill ->
// 20-100MB of scratch HBM traffic. So: NO min-waves clause. The R1-proven
// 4-tile fragment set compiles to ~56 regs, which is <= 64 = the natural
// threshold for 8 waves/SIMD -> TWO 16-wave blocks co-resident per CU
// (32 waves = CU capacity) without any cap.
// Structure: 512 blocks x 1024 thr; 256 rows/block in 2 chunks of 128, both
// staged up-front (trunc-bf16, frag order); wave owns 64 codes (ae 32 + e2f 16
// regs, e2f is the MFMA C operand); merge(c1) ∥ epilogue(c0) pipeline; 4
// barriers. Numerics bitwise-identical to R1-R4 (same operands, same MFMA
// chain, same packed score|code argmax).
__global__ __launch_bounds__(1024) void score_kernel(const float* __restrict__ X,
                                                     const unsigned short* __restrict__ ehT,
                                                     const float* __restrict__ e2g,
                                                     int* __restrict__ hist,
                                                     float* __restrict__ wavesum,
                                                     float* __restrict__ q) {
    __shared__ unsigned short xbuf[2][8192];   // 2 x 16 KB: 128 rows x 64 d, frag order
    __shared__ float mrg[2][128 * 17];         // per-row packed best per wave (stride 17)
    __shared__ int idxl[256];                  // winning code per row
    __shared__ float redL[16];

    const int tid = threadIdx.x;
    const int wave = tid >> 6;
    const int lane = tid & 63;
    const int quad = lane >> 4;
    const int lc = lane & 15;
    const size_t row0 = (size_t)blockIdx.x * 256;

    // ---- stage BOTH chunks: thread n -> LDS 16B unit n = (t=n>>7, o=(n>>4)&7,
    // ls=n&15) holding bf16 X[t*16+ls][o*8..+8]; global read fully coalesced.
    const int st = tid >> 7, so = (tid >> 4) & 7, sl = tid & 15;
    const float* sbase = X + (row0 + (size_t)(st * 16 + sl)) * D + so * 8;
#pragma unroll
    for (int c = 0; c < 2; ++c) {
        float4 La = *(const float4*)(sbase + c * 8192);
        float4 Lb = *(const float4*)(sbase + c * 8192 + 4);
        union { u32 u[4]; short8 v; } pk;
        pk.u[0] = __builtin_amdgcn_perm(__float_as_uint(La.y), __float_as_uint(La.x), 0x07060302);
        pk.u[1] = __builtin_amdgcn_perm(__float_as_uint(La.w), __float_as_uint(La.z), 0x07060302);
        pk.u[2] = __builtin_amdgcn_perm(__float_as_uint(Lb.y), __float_as_uint(Lb.x), 0x07060302);
        pk.u[3] = __builtin_amdgcn_perm(__float_as_uint(Lb.w), __float_as_uint(Lb.z), 0x07060302);
        *(short8*)((char*)&xbuf[c][0] + tid * 16) = pk.v;
    }

    // ---- persistent codebook fragments: wave owns codes [wave*64, wave*64+64) ----
    const int cbase = wave * 64;
    short8 ae[4][2];      // [code-tile][kslice]: code=tile*16+lc, d=ks*32+quad*8..+8
    f32x4 e2f[4];         // -0.5||e||^2 for codes tile*16+quad*4..+4 (MFMA C operand)
#pragma unroll
    for (int ct = 0; ct < 4; ++ct) {
        const unsigned short* ap = ehT + ((size_t)(cbase + ct * 16 + lc) << 6) + quad * 8;
        ae[ct][0] = *(const short8*)(ap);
        ae[ct][1] = *(const short8*)(ap + 32);
        e2f[ct] = *(const f32x4*)(e2g + cbase + ct * 16 + quad * 4);
    }
    const u32 cb0 = (u32)(cbase + quad * 4);

    __syncthreads();   // B1: both chunks staged

    // ---- compute macro: chunk c -> mrg[c] ----
    auto compute = [&](int c) {
        const char* bb = (const char*)&xbuf[c][0];
#pragma unroll 2
        for (int t = 0; t < 8; ++t) {
            const char* bp = bb + t * 2048 + quad * 256 + lc * 16;
            short8 b0 = *(const short8*)(bp);           // ks0
            short8 b1 = *(const short8*)(bp + 1024);    // ks1
            float bt = -3.4e38f;
#pragma unroll
            for (int ct = 0; ct < 4; ++ct) {
                f32x4 acc = __builtin_amdgcn_mfma_f32_16x16x32_bf16(ae[ct][0], b0, e2f[ct], 0, 0, 0);
                acc = __builtin_amdgcn_mfma_f32_16x16x32_bf16(ae[ct][1], b1, acc, 0, 0, 0);
                // acc[r] = score(code = cb0 + ct*16 + r, xrow = t*16+lc)
                float p0 = __uint_as_float((__float_as_uint(acc[0]) & 0xFFFFFC00u) | (cb0 + ct * 16 + 0));
                float p1 = __uint_as_float((__float_as_uint(acc[1]) & 0xFFFFFC00u) | (cb0 + ct * 16 + 1));
                float p2 = __uint_as_float((__float_as_uint(acc[2]) & 0xFFFFFC00u) | (cb0 + ct * 16 + 2));
                float p3 = __uint_as_float((__float_as_uint(acc[3]) & 0xFFFFFC00u) | (cb0 + ct * 16 + 3));
                bt = fmaxf(bt, fmaxf(p0, p1));   // v_max3
                bt = fmaxf(bt, fmaxf(p2, p3));   // v_max3
            }
            bt = fmaxf(bt, __shfl_xor(bt, 16, 64));
            bt = fmaxf(bt, __shfl_xor(bt, 32, 64));
            if (lane < 16) mrg[c][(t * 16 + lane) * 17 + wave] = bt;
        }
    };

    // ---- merge macro: mrg[c] -> idxl[c*128..), hist (128 threads) ----
    auto merge = [&](int c) {
        if (tid < 128) {
            float m = mrg[c][tid * 17];
#pragma unroll
            for (int w = 1; w < 16; ++w) m = fmaxf(m, mrg[c][tid * 17 + w]);
            int kk = (int)(__float_as_uint(m) & 1023u);
            idxl[c * 128 + tid] = kk;
            atomicAdd(&hist[kk], 1);
        }
    };

    // ---- epilogue macro: half h = rows h*128 .. h*128+128, coalesced ----
    float ls = 0.f;
    const int er = tid >> 4, el = tid & 15;
    auto epilogue = [&](int h) {
#pragma unroll
        for (int it = 0; it < 2; ++it) {
            int rl = h * 128 + it * 64 + er;
            int k = idxl[rl];                       // broadcast within 16-thread group
            size_t row = row0 + rl;
            float4 xv = *(const float4*)(X + row * D + el * 4);
            short4 ev = *(const short4*)((const char*)ehT + (size_t)k * 128 + el * 8);
            float4 o;
            float dd;
            dd = b2f(ev.x) - xv.x; ls = fmaf(dd, dd, ls); o.x = xv.x + dd;
            dd = b2f(ev.y) - xv.y; ls = fmaf(dd, dd, ls); o.y = xv.y + dd;
            dd = b2f(ev.z) - xv.z; ls = fmaf(dd, dd, ls); o.z = xv.z + dd;
            dd = b2f(ev.w) - xv.w; ls = fmaf(dd, dd, ls); o.w = xv.w + dd;
            *(float4*)(q + row * D + el * 4) = o;
        }
    };

    compute(0);
    __syncthreads();   // B2: mrg[0] visible
    merge(0);          // idxl[0..128)
    compute(1);
    __syncthreads();   // B3: mrg[1] + idxl[0..128) visible
    merge(1);          // idxl[128..256)   ∥ epilogue(0) on other threads
    epilogue(0);       // reads idxl[0..128) (written before B3; disjoint from merge(1) writes)
    __syncthreads();   // B4: idxl[128..256) visible
    epilogue(1);

    // ---- block loss reduction ----
    for (int off = 32; off > 0; off >>= 1) ls += __shfl_down(ls, off, 64);
    if (lane == 0) redL[wave] = ls;
    __syncthreads();
    if (tid == 0) {
        float L = 0.f;
#pragma unroll
        for (int i = 0; i < 16; ++i) L += redL[i];
        wavesum[blockIdx.x] = L;
    }
}

__global__ __launch_bounds__(1024) void finalize_kernel(const int* __restrict__ hist,
                                                        const float* __restrict__ wavesum,
                                                        float* __restrict__ out) {
    __shared__ float redH[16], redL[16];
    int tid = threadIdx.x;
    float p = (float)hist[tid] * (1.0f / (float)NROWS);
    float term = p * logf(p + 1e-10f);
    float ls = (tid < 512) ? wavesum[tid] : 0.f;
    for (int off = 32; off > 0; off >>= 1) {
        term += __shfl_down(term, off, 64);
        ls += __shfl_down(ls, off, 64);
    }
    int lane = tid & 63, wid = tid >> 6;
    if (lane == 0) { redH[wid] = term; redL[wid] = ls; }
    __syncthreads();
    if (tid == 0) {
        float H = 0.f, L = 0.f;
#pragma unroll
        for (int i = 0; i < 16; ++i) { H += redH[i]; L += redL[i]; }
        out[(size_t)NROWS * D + 0] = 2.0f * (L / (float)(NROWS * D));
        out[(size_t)NROWS * D + 1] = expf(-H);
    }
}

extern "C" void kernel_launch(void* const* d_in, const int* in_sizes, int n_in,
                              void* d_out, int out_size, void* d_ws, size_t ws_size,
                              hipStream_t stream) {
    const float* X = (const float*)d_in[0];   // [64,2048,64] fp32
    const float* E = (const float*)d_in[1];   // [64,1024]   fp32
    float* out = (float*)d_out;

    char* w = (char*)d_ws;
    unsigned short* ehT = (unsigned short*)(w + 0);
    float* e2g          = (float*)(w + 131072);
    int* hist           = (int*)(w + 135168);
    float* wavesum      = (float*)(w + 139264);

    prep_kernel<<<16, 256, 0, stream>>>(E, ehT, e2g, hist);
    score_kernel<<<512, 1024, 0, stream>>>(X, ehT, e2g, hist, wavesum, out);
    finalize_kernel<<<1, 1024, 0, stream>>>(hist, wavesum, out);
}

// Round 6
// 126.524 us; speedup vs baseline: 1.2596x; 1.0001x over previous
//
#include <hip/hip_runtime.h>

#define NROWS 131072
#define D 64
#define K 1024

typedef __attribute__((ext_vector_type(8))) short short8;
typedef __attribute__((ext_vector_type(4))) float f32x4;
typedef unsigned int u32;

// ws layout (bytes):
//   [0, 131072)        ehT  ushort[1024][64]  bf16 codebook, [code][d]
//   [131072, 135168)   e2g  float[1024]       = -0.5*||e_k||^2
//   [135168, 139264)   hist int[1024]
//   [139264, 143360)   wavesum float[1024]  (one per score block)

__device__ __forceinline__ unsigned short f2bf_rne(float f) {
    u32 u = __float_as_uint(f);
    u += 0x7fff + ((u >> 16) & 1);   // round-to-nearest-even
    return (unsigned short)(u >> 16);
}

__device__ __forceinline__ float b2f(short s) {
    return __uint_as_float(((u32)(unsigned short)s) << 16);
}

// 16 blocks x 256 threads: block handles 64 codes, thread = (code, d-quarter).
__global__ __launch_bounds__(256) void prep_kernel(const float* __restrict__ E,
                                                   unsigned short* __restrict__ ehT,
                                                   float* __restrict__ e2g,
                                                   int* __restrict__ hist) {
    __shared__ float ps[4][64];
    const int lane = threadIdx.x & 63;          // code offset within block
    const int w = threadIdx.x >> 6;             // d-quarter 0..3
    const int k = blockIdx.x * 64 + lane;
    float s = 0.f;
#pragma unroll
    for (int half = 0; half < 2; ++half) {
        short8 h8;
#pragma unroll
        for (int j = 0; j < 8; ++j) {
            float v = E[(w * 16 + half * 8 + j) * K + k];   // coalesced across lanes
            s = fmaf(v, v, s);
            h8[j] = (short)f2bf_rne(v);
        }
        *(short8*)(ehT + (size_t)k * D + w * 16 + half * 8) = h8;
    }
    ps[w][lane] = s;
    __syncthreads();
    if (w == 0) e2g[k] = -0.5f * (ps[0][lane] + ps[1][lane] + ps[2][lane] + ps[3][lane]);
    if (threadIdx.x < 64) hist[blockIdx.x * 64 + threadIdx.x] = 0;
}

// R12: small barrier groups. LESSON (R5): VGPR_Count=52 was arch-only; the
// ae/e2f fragments live in AGPRs (unified file) -> true footprint ~100/wave ->
// max 5 waves/SIMD -> a 16-wave block can NEVER have a second block co-resident
// (needs 8/SIMD). So: 256-thread blocks (4 waves = 1 wave/SIMD each). At ~100
// regs, 4-5 blocks/CU co-reside; each block's barriers/merge/epilogue hide
// under the other blocks' MFMA. Each wave sweeps 4 code-groups of 64 (ae 32 +
// e2f 16 regs reloaded per group from L2-resident ehT/e2g; per-row LDS+MFMA
// work invariant), folding the packed best into 8 per-t registers; one shfl
// reduce at the end. 128 rows/block, grid 1024 (= 4 blocks/CU), 3 barriers.
// Numerics: identical operands + MFMA chain; packed score|code values are
// unique (code id in low bits) so fmax order across groups can't change any
// argmax -> q/hist identical to R1-R5.
__global__ __launch_bounds__(256) void score_kernel(const float* __restrict__ X,
                                                    const unsigned short* __restrict__ ehT,
                                                    const float* __restrict__ e2g,
                                                    int* __restrict__ hist,
                                                    float* __restrict__ wavesum,
                                                    float* __restrict__ q) {
    __shared__ unsigned short xbuf[8192];   // 16 KB: 128 rows x 64 d, frag order
    __shared__ float mrg[128 * 5];          // per-row packed best per wave (stride 5)
    __shared__ int idxl[128];               // winning code per row
    __shared__ float redL[4];

    const int tid = threadIdx.x;            // 0..255
    const int wave = tid >> 6;              // 0..3
    const int lane = tid & 63;
    const int quad = lane >> 4;
    const int lc = lane & 15;
    const size_t row0 = (size_t)blockIdx.x * 128;

    // ---- stage 128 rows: 16B unit u = (t=u>>7, o=(u>>4)&7, ls=u&15) holds
    // bf16 X[t*16+ls][o*8..+8]; thread does units {tid + j*256}.
#pragma unroll
    for (int j = 0; j < 4; ++j) {
        int u = tid + j * 256;
        int tt = u >> 7, oo = (u >> 4) & 7, ll = u & 15;
        const float* xp = X + (row0 + (size_t)(tt * 16 + ll)) * D + oo * 8;
        float4 La = *(const float4*)(xp);
        float4 Lb = *(const float4*)(xp + 4);
        union { u32 uu[4]; short8 v; } pk;
        pk.uu[0] = __builtin_amdgcn_perm(__float_as_uint(La.y), __float_as_uint(La.x), 0x07060302);
        pk.uu[1] = __builtin_amdgcn_perm(__float_as_uint(La.w), __float_as_uint(La.z), 0x07060302);
        pk.uu[2] = __builtin_amdgcn_perm(__float_as_uint(Lb.y), __float_as_uint(Lb.x), 0x07060302);
        pk.uu[3] = __builtin_amdgcn_perm(__float_as_uint(Lb.w), __float_as_uint(Lb.z), 0x07060302);
        *(short8*)((char*)&xbuf[0] + u * 16) = pk.v;
    }
    __syncthreads();   // B1: chunk staged

    // ---- per-t packed best, accumulated across 4 code-groups ----
    float bt8[8];
#pragma unroll
    for (int t = 0; t < 8; ++t) bt8[t] = -3.4e38f;

#pragma unroll 1
    for (int h = 0; h < 4; ++h) {
        // this wave's code group for this sweep: 64 codes
        const int cg = h * 256 + wave * 64;
        short8 ae[4][2];   // [code-tile][kslice]: code=cg+ct*16+lc, d=ks*32+quad*8..+8
        f32x4 e2f[4];      // -0.5||e||^2 for codes cg+ct*16+quad*4..+4 (MFMA C operand)
#pragma unroll
        for (int ct = 0; ct < 4; ++ct) {
            const unsigned short* ap = ehT + ((size_t)(cg + ct * 16 + lc) << 6) + quad * 8;
            ae[ct][0] = *(const short8*)(ap);
            ae[ct][1] = *(const short8*)(ap + 32);
            e2f[ct] = *(const f32x4*)(e2g + cg + ct * 16 + quad * 4);
        }
        const u32 cb0 = (u32)(cg + quad * 4);

#pragma unroll 2
        for (int t = 0; t < 8; ++t) {
            const char* bp = (const char*)&xbuf[0] + t * 2048 + quad * 256 + lc * 16;
            short8 b0 = *(const short8*)(bp);           // ks0: row t*16+lc, d quad*8..+8
            short8 b1 = *(const short8*)(bp + 1024);    // ks1
            float bt = bt8[t];
#pragma unroll
            for (int ct = 0; ct < 4; ++ct) {
                f32x4 acc = __builtin_amdgcn_mfma_f32_16x16x32_bf16(ae[ct][0], b0, e2f[ct], 0, 0, 0);
                acc = __builtin_amdgcn_mfma_f32_16x16x32_bf16(ae[ct][1], b1, acc, 0, 0, 0);
                // acc[r] = score(code = cb0 + ct*16 + r, xrow = t*16+lc)
                float p0 = __uint_as_float((__float_as_uint(acc[0]) & 0xFFFFFC00u) | (cb0 + ct * 16 + 0));
                float p1 = __uint_as_float((__float_as_uint(acc[1]) & 0xFFFFFC00u) | (cb0 + ct * 16 + 1));
                float p2 = __uint_as_float((__float_as_uint(acc[2]) & 0xFFFFFC00u) | (cb0 + ct * 16 + 2));
                float p3 = __uint_as_float((__float_as_uint(acc[3]) & 0xFFFFFC00u) | (cb0 + ct * 16 + 3));
                bt = fmaxf(bt, fmaxf(p0, p1));   // v_max3
                bt = fmaxf(bt, fmaxf(p2, p3));   // v_max3
            }
            bt8[t] = bt;
        }
    }

    // ---- one shfl reduce per t (codes live across quad-groups), publish ----
#pragma unroll
    for (int t = 0; t < 8; ++t) {
        float bt = bt8[t];
        bt = fmaxf(bt, __shfl_xor(bt, 16, 64));
        bt = fmaxf(bt, __shfl_xor(bt, 32, 64));
        if (lane < 16) mrg[(t * 16 + lane) * 5 + wave] = bt;
    }
    __syncthreads();   // B2: mrg visible

    // ---- merge + hist (2 waves; other 2 idle briefly — hidden by co-resident blocks) ----
    if (tid < 128) {
        float m = fmaxf(fmaxf(mrg[tid * 5 + 0], mrg[tid * 5 + 1]),
                        fmaxf(mrg[tid * 5 + 2], mrg[tid * 5 + 3]));
        int kk = (int)(__float_as_uint(m) & 1023u);
        idxl[tid] = kk;
        atomicAdd(&hist[kk], 1);
    }
    __syncthreads();   // B3: idxl visible

    // ---- coalesced epilogue: 8 iters x 16 rows; 16 threads/row ----
    float ls = 0.f;
    const int er = tid >> 4, el = tid & 15;   // er 0..15
#pragma unroll 2
    for (int it = 0; it < 8; ++it) {
        int rl = it * 16 + er;
        int k = idxl[rl];                     // broadcast within 16-thread group
        size_t row = row0 + rl;
        float4 xv = *(const float4*)(X + row * D + el * 4);
        short4 ev = *(const short4*)((const char*)ehT + (size_t)k * 128 + el * 8);
        float4 o;
        float dd;
        dd = b2f(ev.x) - xv.x; ls = fmaf(dd, dd, ls); o.x = xv.x + dd;
        dd = b2f(ev.y) - xv.y; ls = fmaf(dd, dd, ls); o.y = xv.y + dd;
        dd = b2f(ev.z) - xv.z; ls = fmaf(dd, dd, ls); o.z = xv.z + dd;
        dd = b2f(ev.w) - xv.w; ls = fmaf(dd, dd, ls); o.w = xv.w + dd;
        *(float4*)(q + row * D + el * 4) = o;
    }
    for (int off = 32; off > 0; off >>= 1) ls += __shfl_down(ls, off, 64);
    if (lane == 0) redL[wave] = ls;
    __syncthreads();
    if (tid == 0)
        wavesum[blockIdx.x] = redL[0] + redL[1] + redL[2] + redL[3];
}

__global__ __launch_bounds__(1024) void finalize_kernel(const int* __restrict__ hist,
                                                        const float* __restrict__ wavesum,
                                                        float* __restrict__ out) {
    __shared__ float redH[16], redL[16];
    int tid = threadIdx.x;
    float p = (float)hist[tid] * (1.0f / (float)NROWS);
    float term = p * logf(p + 1e-10f);
    float ls = wavesum[tid];
    for (int off = 32; off > 0; off >>= 1) {
        term += __shfl_down(term, off, 64);
        ls += __shfl_down(ls, off, 64);
    }
    int lane = tid & 63, wid = tid >> 6;
    if (lane == 0) { redH[wid] = term; redL[wid] = ls; }
    __syncthreads();
    if (tid == 0) {
        float H = 0.f, L = 0.f;
#pragma unroll
        for (int i = 0; i < 16; ++i) { H += redH[i]; L += redL[i]; }
        out[(size_t)NROWS * D + 0] = 2.0f * (L / (float)(NROWS * D));
        out[(size_t)NROWS * D + 1] = expf(-H);
    }
}

extern "C" void kernel_launch(void* const* d_in, const int* in_sizes, int n_in,
                              void* d_out, int out_size, void* d_ws, size_t ws_size,
                              hipStream_t stream) {
    const float* X = (const float*)d_in[0];   // [64,2048,64] fp32
    const float* E = (const float*)d_in[1];   // [64,1024]   fp32
    float* out = (float*)d_out;

    char* w = (char*)d_ws;
    unsigned short* ehT = (unsigned short*)(w + 0);
    float* e2g          = (float*)(w + 131072);
    int* hist           = (int*)(w + 135168);
    float* wavesum      = (float*)(w + 139264);

    prep_kernel<<<16, 256, 0, stream>>>(E, ehT, e2g, hist);
    score_kernel<<<NROWS / 128, 256, 0, stream>>>(X, ehT, e2g, hist, wavesum, out);
    finalize_kernel<<<1, 1024, 0, stream>>>(hist, wavesum, out);
}

// Round 7
// 122.054 us; speedup vs baseline: 1.3058x; 1.0366x over previous
//
#include <hip/hip_runtime.h>

#define NROWS 131072
#define D 64
#define K 1024

typedef __attribute__((ext_vector_type(8))) short short8;
typedef __attribute__((ext_vector_type(4))) float f32x4;
typedef unsigned int u32;

// ws layout (bytes):
//   [0, 131072)        ehT  ushort[1024][64]  bf16 codebook, [code][d]
//   [131072, 135168)   e2g  float[1024]       = -0.5*||e_k||^2
//   [135168, 139264)   hist int[1024]
//   [139264, 143360)   wavesum float[256]  (one per score block)

__device__ __forceinline__ unsigned short f2bf_rne(float f) {
    u32 u = __float_as_uint(f);
    u += 0x7fff + ((u >> 16) & 1);   // round-to-nearest-even
    return (unsigned short)(u >> 16);
}

__device__ __forceinline__ float b2f(short s) {
    return __uint_as_float(((u32)(unsigned short)s) << 16);
}

// 16 blocks x 256 threads: block handles 64 codes, thread = (code, d-quarter).
__global__ __launch_bounds__(256) void prep_kernel(const float* __restrict__ E,
                                                   unsigned short* __restrict__ ehT,
                                                   float* __restrict__ e2g,
                                                   int* __restrict__ hist) {
    __shared__ float ps[4][64];
    const int lane = threadIdx.x & 63;          // code offset within block
    const int w = threadIdx.x >> 6;             // d-quarter 0..3
    const int k = blockIdx.x * 64 + lane;
    float s = 0.f;
#pragma unroll
    for (int half = 0; half < 2; ++half) {
        short8 h8;
#pragma unroll
        for (int j = 0; j < 8; ++j) {
            float v = E[(w * 16 + half * 8 + j) * K + k];   // coalesced across lanes
            s = fmaf(v, v, s);
            h8[j] = (short)f2bf_rne(v);
        }
        *(short8*)(ehT + (size_t)k * D + w * 16 + half * 8) = h8;
    }
    ps[w][lane] = s;
    __syncthreads();
    if (w == 0) e2g[k] = -0.5f * (ps[0][lane] + ps[1][lane] + ps[2][lane] + ps[3][lane]);
    if (threadIdx.x < 64) hist[blockIdx.x * 64 + threadIdx.x] = 0;
}

// R13 = R1 (best measured, 49.9us) + three serial-chain cuts:
//  (1) fused per-chunk epilogue with NO X re-read: q = bf16 codebook row
//      (== x + (e-x); R2-proven, same absmax), loss from the staged LDS bf16 x.
//      Gather latency hides under the next chunk's MFMA.
//  (2) batched reduce: packed best accumulated in bt8[8] across the t-loop;
//      the 8 shfl_xor pairs run afterward as independent chains (8x MLP on
//      the ~120cyc lgkm latency) instead of 8 inline dependent pairs.
//  (3) unchanged R1 skeleton: 256 blocks x 16 waves, 512 rows/block in 4
//      chunks, issue-early staging, NO launch-bounds cap (R2-R4 lesson: any
//      total-reg cap below the ~90-reg working set -> scratch poison).
// Numerics: identical operands + MFMA chain + packed score|code argmax ->
// same q/hist as R1-R6; absmax 0.4326172.
__global__ __launch_bounds__(1024) void score_kernel(const float* __restrict__ X,
                                                     const unsigned short* __restrict__ ehT,
                                                     const float* __restrict__ e2g,
                                                     int* __restrict__ hist,
                                                     float* __restrict__ wavesum,
                                                     float* __restrict__ q) {
    __shared__ unsigned short xbuf[2][8192];   // 2 x 16 KB: 128 rows x 64 d, frag order
    __shared__ float mrg[2][128 * 17];         // per-row packed best per wave (stride 17)
    __shared__ int idxl[2][128];               // winning code per row, double-buffered
    __shared__ float redL[16];

    const int tid = threadIdx.x;
    const int wave = tid >> 6;
    const int lane = tid & 63;
    const int quad = lane >> 4;
    const int lc = lane & 15;
    const size_t row0 = (size_t)blockIdx.x * 512;

    // ---- stage mapping: thread n -> LDS 16B unit n = (t=n>>7, o=(n>>4)&7,
    // ls=n&15) holding bf16 X[t*16+ls][o*8..+8]; global read fully coalesced.
    const int st = tid >> 7, so = (tid >> 4) & 7, sl = tid & 15;
    const int rowl = st * 16 + sl;             // this thread's staged row (0..127)
    const float* sbase = X + (row0 + (size_t)rowl) * D + so * 8;

    // ---- prologue: stage chunk 0 ----
    {
        float4 La = *(const float4*)(sbase);
        float4 Lb = *(const float4*)(sbase + 4);
        union { u32 u[4]; short8 v; } pk;
        pk.u[0] = __builtin_amdgcn_perm(__float_as_uint(La.y), __float_as_uint(La.x), 0x07060302);
        pk.u[1] = __builtin_amdgcn_perm(__float_as_uint(La.w), __float_as_uint(La.z), 0x07060302);
        pk.u[2] = __builtin_amdgcn_perm(__float_as_uint(Lb.y), __float_as_uint(Lb.x), 0x07060302);
        pk.u[3] = __builtin_amdgcn_perm(__float_as_uint(Lb.w), __float_as_uint(Lb.z), 0x07060302);
        *(short8*)((char*)&xbuf[0][0] + tid * 16) = pk.v;
    }

    // ---- persistent codebook fragments: wave owns codes [wave*64, wave*64+64) ----
    const int cbase = wave * 64;
    short8 ae[4][2];      // [code-tile][kslice]: code=tile*16+lc, d=ks*32+quad*8..+8
    f32x4 e2f[4];         // -0.5||e||^2 for codes tile*16+quad*4..+4 (MFMA C operand)
#pragma unroll
    for (int ct = 0; ct < 4; ++ct) {
        const unsigned short* ap = ehT + ((size_t)(cbase + ct * 16 + lc) << 6) + quad * 8;
        ae[ct][0] = *(const short8*)(ap);
        ae[ct][1] = *(const short8*)(ap + 32);
        e2f[ct] = *(const f32x4*)(e2g + cbase + ct * 16 + quad * 4);
    }
    const u32 cb0 = (u32)(cbase + quad * 4);

    __syncthreads();   // B1: chunk 0 staged

    float ls = 0.f;
    for (int c = 0; c < 4; ++c) {
        const int cur = c & 1;
        // issue-early global loads for chunk c+1 (land during compute; the
        // vmcnt wait sits at the stage-write after B2, long past latency)
        float4 La, Lb;
        if (c < 3) {
            La = *(const float4*)(sbase + (c + 1) * 8192);
            Lb = *(const float4*)(sbase + (c + 1) * 8192 + 4);
        }

        // ---- compute chunk c: pure ds_read + MFMA + max3 into bt8 ----
        float bt8[8];
        const char* bb = (const char*)&xbuf[cur][0];
#pragma unroll 2
        for (int t = 0; t < 8; ++t) {
            const char* bp = bb + t * 2048 + quad * 256 + lc * 16;
            short8 b0 = *(const short8*)(bp);           // ks0
            short8 b1 = *(const short8*)(bp + 1024);    // ks1
            float bt = -3.4e38f;
#pragma unroll
            for (int ct = 0; ct < 4; ++ct) {
                f32x4 acc = __builtin_amdgcn_mfma_f32_16x16x32_bf16(ae[ct][0], b0, e2f[ct], 0, 0, 0);
                acc = __builtin_amdgcn_mfma_f32_16x16x32_bf16(ae[ct][1], b1, acc, 0, 0, 0);
                // acc[r] = score(code = cb0 + ct*16 + r, xrow = t*16+lc)
                float p0 = __uint_as_float((__float_as_uint(acc[0]) & 0xFFFFFC00u) | (cb0 + ct * 16 + 0));
                float p1 = __uint_as_float((__float_as_uint(acc[1]) & 0xFFFFFC00u) | (cb0 + ct * 16 + 1));
                float p2 = __uint_as_float((__float_as_uint(acc[2]) & 0xFFFFFC00u) | (cb0 + ct * 16 + 2));
                float p3 = __uint_as_float((__float_as_uint(acc[3]) & 0xFFFFFC00u) | (cb0 + ct * 16 + 3));
                bt = fmaxf(bt, fmaxf(p0, p1));   // v_max3
                bt = fmaxf(bt, fmaxf(p2, p3));   // v_max3
            }
            bt8[t] = bt;
        }
        // ---- batched cross-lane reduce: 8 independent shfl chains ----
#pragma unroll
        for (int t = 0; t < 8; ++t) {
            float bt = bt8[t];
            bt = fmaxf(bt, __shfl_xor(bt, 16, 64));
            bt = fmaxf(bt, __shfl_xor(bt, 32, 64));
            if (lane < 16) mrg[cur][(t * 16 + lane) * 17 + wave] = bt;
        }
        __syncthreads();   // B2: mrg[cur] visible

        // ---- merge (128 thr) ∥ stage-write c+1 (all) ----
        if (tid < 128) {
            float m = mrg[cur][tid * 17];
#pragma unroll
            for (int w = 1; w < 16; ++w) m = fmaxf(m, mrg[cur][tid * 17 + w]);
            int kk = (int)(__float_as_uint(m) & 1023u);
            idxl[cur][tid] = kk;
            atomicAdd(&hist[kk], 1);
        }
        if (c < 3) {
            union { u32 u[4]; short8 v; } pk;
            pk.u[0] = __builtin_amdgcn_perm(__float_as_uint(La.y), __float_as_uint(La.x), 0x07060302);
            pk.u[1] = __builtin_amdgcn_perm(__float_as_uint(La.w), __float_as_uint(La.z), 0x07060302);
            pk.u[2] = __builtin_amdgcn_perm(__float_as_uint(Lb.y), __float_as_uint(Lb.x), 0x07060302);
            pk.u[3] = __builtin_amdgcn_perm(__float_as_uint(Lb.w), __float_as_uint(Lb.z), 0x07060302);
            *(short8*)((char*)&xbuf[cur ^ 1][0] + tid * 16) = pk.v;
        }
        __syncthreads();   // B3: idxl[cur] + staged chunk visible

        // ---- fused epilogue chunk c: own staged slice; q = e_bf16; no X read.
        // Interleaves with the next chunk's compute (independent pipes).
        {
            int kk = idxl[cur][rowl];                 // broadcast among 8 so-threads
            short8 ev = *(const short8*)(ehT + ((size_t)kk << 6) + so * 8);
            short8 xv = *(const short8*)(&xbuf[cur][tid * 8]);
            float4 qa, qb;
            float e0, dd;
            e0 = b2f(ev[0]); dd = e0 - b2f(xv[0]); ls = fmaf(dd, dd, ls); qa.x = e0;
            e0 = b2f(ev[1]); dd = e0 - b2f(xv[1]); ls = fmaf(dd, dd, ls); qa.y = e0;
            e0 = b2f(ev[2]); dd = e0 - b2f(xv[2]); ls = fmaf(dd, dd, ls); qa.z = e0;
            e0 = b2f(ev[3]); dd = e0 - b2f(xv[3]); ls = fmaf(dd, dd, ls); qa.w = e0;
            e0 = b2f(ev[4]); dd = e0 - b2f(xv[4]); ls = fmaf(dd, dd, ls); qb.x = e0;
            e0 = b2f(ev[5]); dd = e0 - b2f(xv[5]); ls = fmaf(dd, dd, ls); qb.y = e0;
            e0 = b2f(ev[6]); dd = e0 - b2f(xv[6]); ls = fmaf(dd, dd, ls); qb.z = e0;
            e0 = b2f(ev[7]); dd = e0 - b2f(xv[7]); ls = fmaf(dd, dd, ls); qb.w = e0;
            float* qp = q + (row0 + (size_t)(c * 128 + rowl)) * D + so * 8;
            *(float4*)(qp) = qa;
            *(float4*)(qp + 4) = qb;
        }
    }

    // ---- block loss reduction ----
    for (int off = 32; off > 0; off >>= 1) ls += __shfl_down(ls, off, 64);
    if (lane == 0) redL[wave] = ls;
    __syncthreads();
    if (tid == 0) {
        float L = 0.f;
#pragma unroll
        for (int i = 0; i < 16; ++i) L += redL[i];
        wavesum[blockIdx.x] = L;
    }
}

__global__ __launch_bounds__(1024) void finalize_kernel(const int* __restrict__ hist,
                                                        const float* __restrict__ wavesum,
                                                        float* __restrict__ out) {
    __shared__ float redH[16], redL[16];
    int tid = threadIdx.x;
    float p = (float)hist[tid] * (1.0f / (float)NROWS);
    float term = p * logf(p + 1e-10f);
    float ls = (tid < 256) ? wavesum[tid] : 0.f;
    for (int off = 32; off > 0; off >>= 1) {
        term += __shfl_down(term, off, 64);
        ls += __shfl_down(ls, off, 64);
    }
    int lane = tid & 63, wid = tid >> 6;
    if (lane == 0) { redH[wid] = term; redL[wid] = ls; }
    __syncthreads();
    if (tid == 0) {
        float H = 0.f, L = 0.f;
#pragma unroll
        for (int i = 0; i < 16; ++i) { H += redH[i]; L += redL[i]; }
        out[(size_t)NROWS * D + 0] = 2.0f * (L / (float)(NROWS * D));
        out[(size_t)NROWS * D + 1] = expf(-H);
    }
}

extern "C" void kernel_launch(void* const* d_in, const int* in_sizes, int n_in,
                              void* d_out, int out_size, void* d_ws, size_t ws_size,
                              hipStream_t stream) {
    const float* X = (const float*)d_in[0];   // [64,2048,64] fp32
    const float* E = (const float*)d_in[1];   // [64,1024]   fp32
    float* out = (float*)d_out;

    char* w = (char*)d_ws;
    unsigned short* ehT = (unsigned short*)(w + 0);
    float* e2g          = (float*)(w + 131072);
    int* hist           = (int*)(w + 135168);
    float* wavesum      = (float*)(w + 139264);

    prep_kernel<<<16, 256, 0, stream>>>(E, ehT, e2g, hist);
    score_kernel<<<NROWS / 512, 1024, 0, stream>>>(X, ehT, e2g, hist, wavesum, out);
    finalize_kernel<<<1, 1024, 0, stream>>>(hist, wavesum, out);
}